// Round 3
// baseline (194.889 us; speedup 1.0000x reference)
//
#include <hip/hip_runtime.h>
#include <stdint.h>

#define BN            16384
#define PHASE_PTS     4096
#define NPHASE        4
#define BLOCK_THREADS 1024
#define KOUT          16
#define SENT          0xFF800000u  // sortable key of +inf

typedef float v2f __attribute__((ext_vector_type(2)));

__device__ __forceinline__ unsigned f2key_u(unsigned u) {
    return u ^ ((unsigned)((int)u >> 31) | 0x80000000u);
}
__device__ __forceinline__ unsigned key2f_u(unsigned t) {
    return t ^ ((unsigned)((int)(~t) >> 31) | 0x80000000u);
}
// whole-wave shift by 1: lane i <- lane i-1, lane 0 keeps old. VALU DPP, no LDS pipe.
__device__ __forceinline__ unsigned wshr1(unsigned v) {
    return (unsigned)__builtin_amdgcn_update_dpp((int)v, (int)v, 0x138, 0xF, 0xF, false);
}

// Sorted-insert of wave-uniform candidate (tc,jc) into lane-distributed sorted list.
// Forced bit 63 keeps ctz defined; a candidate beating nothing self-inserts at
// lane 63 (junk zone, sorted invariant preserved since tc >= T[63] there).
#define INSERT(T, J, tc, jc)                                                   \
    do {                                                                       \
        const uint64_t bal_ = __ballot((tc) < (T)) | 0x8000000000000000ull;    \
        const int pos_ = (int)__builtin_ctzll(bal_);                           \
        const unsigned Tup_ = wshr1(T);                                        \
        const unsigned Jup_ = wshr1(J);                                        \
        (T) = (lane == pos_) ? (tc) : ((lane > pos_) ? Tup_ : (T));            \
        (J) = (lane == pos_) ? (jc) : ((lane > pos_) ? Jup_ : (J));            \
    } while (0)

#define DRAIN(m, p, T, J)                                                      \
    while (m) {                                                                \
        const int b_ = (int)__builtin_ctzll(m);                                \
        m &= m - 1;                                                            \
        const unsigned tc_ =                                                   \
            f2key_u((unsigned)__builtin_amdgcn_readlane(__float_as_int(p), b_)); \
        const unsigned jc_ = (unsigned)(jbase + b_);                           \
        INSERT(T, J, tc_, jc_);                                                \
    }

__device__ __forceinline__ float filt_of(unsigned T) {
    return __uint_as_float(
        key2f_u((unsigned)__builtin_amdgcn_readlane((int)T, 16)));
}

__global__ __launch_bounds__(BLOCK_THREADS) void knn_far_kernel(
    const float* __restrict__ x, float* __restrict__ out_d, float* __restrict__ out_i) {
    extern __shared__ float4 buf[];  // PHASE_PTS float4 = 64KB

    const int tid  = threadIdx.x;
    const int lane = tid & 63;
    const int wid  = tid >> 6;
    const int qb   = (blockIdx.x * (BLOCK_THREADS / 64) + wid) * 4;  // 4 queries/wave

    // Load 4 query points; nsq = -((x^2+y^2)+z^2) in exact np order.
    float QX[4], QY[4], QZ[4], NSQ[4];
#pragma unroll
    for (int c = 0; c < 4; ++c) {
        const float X = x[3 * (qb + c)], Y = x[3 * (qb + c) + 1], Z = x[3 * (qb + c) + 2];
        QX[c] = X; QY[c] = Y; QZ[c] = Z;
        NSQ[c] = -__fadd_rn(__fadd_rn(__fmul_rn(X, X), __fmul_rn(Y, Y)), __fmul_rn(Z, Z));
    }
    // Pre-doubled packed query coeffs (x2 exact; RN(2x*y)=2*RN(x*y), fma likewise,
    // so the pk chain yields exactly 2*dot of the reference fma chain).
    const v2f c0A = {2.0f * QX[0], 2.0f * QX[1]}, c1A = {2.0f * QY[0], 2.0f * QY[1]},
              c2A = {2.0f * QZ[0], 2.0f * QZ[1]};
    const v2f c0B = {2.0f * QX[2], 2.0f * QX[3]}, c1B = {2.0f * QY[2], 2.0f * QY[3]},
              c2B = {2.0f * QZ[2], 2.0f * QZ[3]};

    unsigned T0 = SENT, J0 = 0, T1 = SENT, J1 = 0, T2 = SENT, J2 = 0, T3 = SENT, J3 = 0;
    float f0 = __uint_as_float(0x7F800000u), f1 = f0, f2 = f0, f3 = f0;

    for (int ph = 0; ph < NPHASE; ++ph) {
        __syncthreads();
        const int pbase = ph * PHASE_PTS;
#pragma unroll
        for (int kk = 0; kk < PHASE_PTS / BLOCK_THREADS; ++kk) {
            const int pl = tid + kk * BLOCK_THREADS;
            const int P  = pbase + pl;
            const float gx = x[3 * P], gy = x[3 * P + 1], gz = x[3 * P + 2];
            const float sq = __fadd_rn(__fadd_rn(__fmul_rn(gx, gx), __fmul_rn(gy, gy)),
                                       __fmul_rn(gz, gz));
            buf[pl] = make_float4(gx, gy, gz, sq);
        }
        __syncthreads();

#pragma unroll 4
        for (int tile = 0; tile < PHASE_PTS / 64; ++tile) {
            union F4 { float4 f4; v2f p[2]; float f[4]; } c;
            c.f4 = buf[tile * 64 + lane];
            v2f tA, tB;
            // tA = (2qx*cx, ...) ; broadcast LOW half of src0 via op_sel_hi[0]=0
            asm("v_pk_mul_f32 %0, %1, %2 op_sel:[0,0] op_sel_hi:[0,1]"
                : "=v"(tA) : "v"(c.p[0]), "v"(c0A));
            asm("v_pk_fma_f32 %0, %1, %2, %3 op_sel:[1,0,0] op_sel_hi:[1,1,1]"
                : "=v"(tA) : "v"(c.p[0]), "v"(c1A), "v"(tA));
            asm("v_pk_fma_f32 %0, %1, %2, %3 op_sel:[0,0,0] op_sel_hi:[0,1,1]"
                : "=v"(tA) : "v"(c.p[1]), "v"(c2A), "v"(tA));
            asm("v_pk_mul_f32 %0, %1, %2 op_sel:[0,0] op_sel_hi:[0,1]"
                : "=v"(tB) : "v"(c.p[0]), "v"(c0B));
            asm("v_pk_fma_f32 %0, %1, %2, %3 op_sel:[1,0,0] op_sel_hi:[1,1,1]"
                : "=v"(tB) : "v"(c.p[0]), "v"(c1B), "v"(tB));
            asm("v_pk_fma_f32 %0, %1, %2, %3 op_sel:[0,0,0] op_sel_hi:[0,1,1]"
                : "=v"(tB) : "v"(c.p[1]), "v"(c2B), "v"(tB));
            // p = ((2dot + (-sq_i)) - sq_j): RN(x+(-y))==RN(x-y), bitwise == reference
            const float p0 = __fsub_rn(__fadd_rn(tA[0], NSQ[0]), c.f[3]);
            const float p1 = __fsub_rn(__fadd_rn(tA[1], NSQ[1]), c.f[3]);
            const float p2 = __fsub_rn(__fadd_rn(tB[0], NSQ[2]), c.f[3]);
            const float p3 = __fsub_rn(__fadd_rn(tB[1], NSQ[3]), c.f[3]);

            uint64_t m0 = __ballot(p0 < f0);
            uint64_t m1 = __ballot(p1 < f1);
            uint64_t m2 = __ballot(p2 < f2);
            uint64_t m3 = __ballot(p3 < f3);
            if (m0 | m1 | m2 | m3) {
                const int jbase = pbase + tile * 64;
                DRAIN(m0, p0, T0, J0)
                DRAIN(m1, p1, T1, J1)
                DRAIN(m2, p2, T2, J2)
                DRAIN(m3, p3, T3, J3)
                // rank-16 filter refresh: per tile, not per insert
                f0 = filt_of(T0); f1 = filt_of(T1); f2 = filt_of(T2); f3 = filt_of(T3);
            }
        }
    }

    // ranks 1..16 (rank 0 = the query itself / farthest dropped per reference slicing)
    if (lane >= 1 && lane <= KOUT) {
        const int r = lane - 1;
        out_d[(qb + 0) * KOUT + r] = __uint_as_float(key2f_u(T0));
        out_i[(qb + 0) * KOUT + r] = (float)J0;
        out_d[(qb + 1) * KOUT + r] = __uint_as_float(key2f_u(T1));
        out_i[(qb + 1) * KOUT + r] = (float)J1;
        out_d[(qb + 2) * KOUT + r] = __uint_as_float(key2f_u(T2));
        out_i[(qb + 2) * KOUT + r] = (float)J2;
        out_d[(qb + 3) * KOUT + r] = __uint_as_float(key2f_u(T3));
        out_i[(qb + 3) * KOUT + r] = (float)J3;
    }
}

extern "C" void kernel_launch(void* const* d_in, const int* in_sizes, int n_in,
                              void* d_out, int out_size, void* d_ws, size_t ws_size,
                              hipStream_t stream) {
    const float* x = (const float*)d_in[0];
    float* out_d = (float*)d_out;              // 8*2048*16 dists
    float* out_i = out_d + (size_t)BN * KOUT;  // 8*2048*16 indices (as float)
    const int queries_per_block = 4 * (BLOCK_THREADS / 64);
    hipLaunchKernelGGL(knn_far_kernel, dim3(BN / queries_per_block), dim3(BLOCK_THREADS),
                       PHASE_PTS * sizeof(float4), stream, x, out_d, out_i);
}

// Round 4
// 173.767 us; speedup vs baseline: 1.1216x; 1.1216x over previous
//
#include <hip/hip_runtime.h>
#include <stdint.h>

#define BN            16384
#define PHASE_PTS     4096
#define NPHASE        4
#define BLOCK_THREADS 1024
#define KOUT          16
#define SENTK         0xFF800000u  // sortable key of +inf; key2f(SENTK) == +inf

typedef float v2f __attribute__((ext_vector_type(2)));

__device__ __forceinline__ unsigned f2key_u(unsigned u) {
    return u ^ ((unsigned)((int)u >> 31) | 0x80000000u);
}
__device__ __forceinline__ unsigned key2f_u(unsigned t) {
    return t ^ ((unsigned)((int)(~t) >> 31) | 0x80000000u);
}
// whole-wave shift-right by 1 with 0 shifted into lane 0 (VALU DPP, no LDS pipe)
__device__ __forceinline__ unsigned wshr1_z(unsigned v) {
    return (unsigned)__builtin_amdgcn_update_dpp(0, (int)v, 0x138 /*WAVE_SHR1*/, 0xF, 0xF, false);
}

// Sorted insert of wave-uniform candidate Kc into strictly-ascending lane array K.
// sel = (Kc < K) is a suffix mask starting at the insertion rank; for lanes in sel,
// new value = max(Kc, K[lane-1]) (K[-1]:=0). Empty sel -> no-op (candidate already
// out of top-64: correct drop). No position/ctz math, no LDS-pipe traffic.
#define INSERT64(K, Kc)                                                        \
    do {                                                                       \
        const unsigned lo_ = (unsigned)(K), hi_ = (unsigned)((K) >> 32);       \
        const uint64_t Kup_ = ((uint64_t)wshr1_z(hi_) << 32) | wshr1_z(lo_);   \
        const uint64_t Km_  = ((Kc) > Kup_) ? (Kc) : Kup_;                     \
        (K) = ((Kc) < (K)) ? Km_ : (K);                                        \
    } while (0)

#define DRAIN(m, p, K)                                                         \
    while (m) {                                                                \
        const int b_ = (int)__builtin_ctzll(m);                                \
        m &= m - 1;                                                            \
        const unsigned tc_ =                                                   \
            f2key_u((unsigned)__builtin_amdgcn_readlane(__float_as_int(p), b_)); \
        const uint64_t Kc_ = ((uint64_t)tc_ << 32) | (unsigned)(jbase + b_);   \
        INSERT64(K, Kc_);                                                      \
    }

__device__ __forceinline__ float filt_of(uint64_t K) {
    return __uint_as_float(
        key2f_u((unsigned)__builtin_amdgcn_readlane((int)(unsigned)(K >> 32), 16)));
}

__global__ __launch_bounds__(BLOCK_THREADS) void knn_far_kernel(
    const float* __restrict__ x, float* __restrict__ out_d, float* __restrict__ out_i) {
    extern __shared__ float4 buf[];  // PHASE_PTS float4 = 64KB -> 2 blocks/CU, 32 waves/CU

    const int tid  = threadIdx.x;
    const int lane = tid & 63;
    const int wid  = tid >> 6;
    const int q0   = (blockIdx.x * (BLOCK_THREADS / 64) + wid) * 2;  // 2 queries/wave
    const int q1   = q0 + 1;

    // Query points; nsq = -((x^2+y^2)+z^2) in exact np order.
    const float a0 = x[3 * q0], a1 = x[3 * q0 + 1], a2 = x[3 * q0 + 2];
    const float b0 = x[3 * q1], b1 = x[3 * q1 + 1], b2 = x[3 * q1 + 2];
    const float nsq0 = -__fadd_rn(__fadd_rn(__fmul_rn(a0, a0), __fmul_rn(a1, a1)), __fmul_rn(a2, a2));
    const float nsq1 = -__fadd_rn(__fadd_rn(__fmul_rn(b0, b0), __fmul_rn(b1, b1)), __fmul_rn(b2, b2));
    // Pre-doubled packed query coeffs (x2 exact; RN(2x*y)=2*RN(x*y), fma likewise:
    // pk chain == 2*dot of the reference fma chain, bitwise).
    const v2f c0A = {2.0f * a0, 2.0f * b0};
    const v2f c1A = {2.0f * a1, 2.0f * b1};
    const v2f c2A = {2.0f * a2, 2.0f * b2};

    // Lane-distributed sorted lists (strictly ascending u64 = key<<32 | idx).
    uint64_t K0 = ((uint64_t)SENTK << 32) | (unsigned)lane;
    uint64_t K1 = K0;
    float f0 = __uint_as_float(0x7F800000u), f1 = f0;  // rank-16 filter, +inf until full

    for (int ph = 0; ph < NPHASE; ++ph) {
        __syncthreads();
        const int pbase = ph * PHASE_PTS;
#pragma unroll
        for (int kk = 0; kk < PHASE_PTS / BLOCK_THREADS; ++kk) {
            const int pl = tid + kk * BLOCK_THREADS;
            const int P  = pbase + pl;
            const float gx = x[3 * P], gy = x[3 * P + 1], gz = x[3 * P + 2];
            const float sq = __fadd_rn(__fadd_rn(__fmul_rn(gx, gx), __fmul_rn(gy, gy)),
                                       __fmul_rn(gz, gz));
            buf[pl] = make_float4(gx, gy, gz, sq);
        }
        __syncthreads();

#pragma unroll 4
        for (int tile = 0; tile < PHASE_PTS / 64; ++tile) {
            union F4 { float4 f4; v2f p[2]; float f[4]; } c;
            c.f4 = buf[tile * 64 + lane];
            v2f tA;
            // tA = (2qx*cx, ...) for both queries; broadcast point coord via op_sel
            asm("v_pk_mul_f32 %0, %1, %2 op_sel:[0,0] op_sel_hi:[0,1]"
                : "=v"(tA) : "v"(c.p[0]), "v"(c0A));
            asm("v_pk_fma_f32 %0, %1, %2, %3 op_sel:[1,0,0] op_sel_hi:[1,1,1]"
                : "=v"(tA) : "v"(c.p[0]), "v"(c1A), "v"(tA));
            asm("v_pk_fma_f32 %0, %1, %2, %3 op_sel:[0,0,0] op_sel_hi:[0,1,1]"
                : "=v"(tA) : "v"(c.p[1]), "v"(c2A), "v"(tA));
            // p = ((2dot + (-sq_i)) - sq_j): RN(x+(-y))==RN(x-y) -> bitwise == reference
            const float p0 = __fsub_rn(__fadd_rn(tA[0], nsq0), c.f[3]);
            const float p1 = __fsub_rn(__fadd_rn(tA[1], nsq1), c.f[3]);

            uint64_t m0 = __ballot(p0 < f0);
            uint64_t m1 = __ballot(p1 < f1);
            if (m0 | m1) {
                const int jbase = pbase + tile * 64;
                DRAIN(m0, p0, K0)
                DRAIN(m1, p1, K1)
                f0 = filt_of(K0);  // rank-16 filter refresh once per slow tile
                f1 = filt_of(K1);
            }
        }
    }

    // ranks 1..16 (rank 0 = the farthest / self-pair handling per reference slicing)
    if (lane >= 1 && lane <= KOUT) {
        const int r = lane - 1;
        out_d[q0 * KOUT + r] = __uint_as_float(key2f_u((unsigned)(K0 >> 32)));
        out_i[q0 * KOUT + r] = (float)(unsigned)(K0 & 0xFFFFFFFFu);
        out_d[q1 * KOUT + r] = __uint_as_float(key2f_u((unsigned)(K1 >> 32)));
        out_i[q1 * KOUT + r] = (float)(unsigned)(K1 & 0xFFFFFFFFu);
    }
}

extern "C" void kernel_launch(void* const* d_in, const int* in_sizes, int n_in,
                              void* d_out, int out_size, void* d_ws, size_t ws_size,
                              hipStream_t stream) {
    const float* x = (const float*)d_in[0];
    float* out_d = (float*)d_out;              // 8*2048*16 dists
    float* out_i = out_d + (size_t)BN * KOUT;  // 8*2048*16 indices (as float)
    const int queries_per_block = 2 * (BLOCK_THREADS / 64);
    hipLaunchKernelGGL(knn_far_kernel, dim3(BN / queries_per_block), dim3(BLOCK_THREADS),
                       PHASE_PTS * sizeof(float4), stream, x, out_d, out_i);
}

// Round 5
// 171.283 us; speedup vs baseline: 1.1378x; 1.0145x over previous
//
#include <hip/hip_runtime.h>
#include <stdint.h>

#define BN            16384
#define PHASE_PTS     4096
#define NPHASE        4
#define BLOCK_THREADS 1024
#define KOUT          16

typedef float v2f __attribute__((ext_vector_type(2)));

// sortable key of float bits (ascending uint == ascending float)
__device__ __forceinline__ unsigned key_u(unsigned u) {
    return u ^ ((unsigned)((int)u >> 31) | 0x80000000u);
}
// whole-wave shift-right by 1; lane 0 receives `oldv` (VALU DPP, no LDS pipe)
__device__ __forceinline__ unsigned wshr1(unsigned v, unsigned oldv) {
    return (unsigned)__builtin_amdgcn_update_dpp((int)oldv, (int)v, 0x138 /*WAVE_SHR:1*/,
                                                 0xF, 0xF, false);
}

// Drain set bits of mask m: for each, scalar skip-check against the live rank-16
// filter key fK (SALU), then a 32-bit float-space sorted insert into (T,J):
//   sel = pc < T (suffix mask from insertion rank)
//   lanes in sel: T' = (pc < Tup) ? Tup : pc ; J' = (pc < Tup) ? Jup : jc
// (Tup shifted with -inf into lane 0 so lane 0 always takes the candidate.)
// Then refresh fK/fF from the updated rank-16 so later candidates self-skip.
#define DRAIN(m, p, T, J, fK, fF)                                                   \
    while (m) {                                                                     \
        const int b_ = (int)__builtin_ctzll(m);                                     \
        m &= m - 1;                                                                 \
        const unsigned pu_ =                                                        \
            (unsigned)__builtin_amdgcn_readlane(__float_as_int(p), b_);             \
        if (key_u(pu_) >= (fK)) continue; /* stale candidate: free skip */          \
        const float pc_ = __uint_as_float(pu_);                                     \
        const unsigned jc_ = (unsigned)(jbase + b_);                                \
        const float Tup_ = __uint_as_float(wshr1(__float_as_uint(T), 0xFF800000u)); \
        const unsigned Jup_ = wshr1((J), 0u);                                       \
        const bool lt_ = (pc_ < Tup_);                                              \
        const float Tn_ = lt_ ? Tup_ : pc_;                                         \
        const unsigned Jn_ = lt_ ? Jup_ : jc_;                                      \
        const bool sel_ = (pc_ < (T));                                              \
        (T) = sel_ ? Tn_ : (T);                                                     \
        (J) = sel_ ? Jn_ : (J);                                                     \
        const unsigned t16_ =                                                       \
            (unsigned)__builtin_amdgcn_readlane(__float_as_int(T), 16);             \
        (fK) = key_u(t16_);                                                         \
        (fF) = __uint_as_float(t16_);                                               \
    }

__global__ __launch_bounds__(BLOCK_THREADS) void knn_far_kernel(
    const float* __restrict__ x, float* __restrict__ out_d, float* __restrict__ out_i) {
    extern __shared__ float4 buf[];  // PHASE_PTS float4 = 64KB -> 2 blocks/CU, 32 waves/CU

    const int tid  = threadIdx.x;
    const int lane = tid & 63;
    const int wid  = tid >> 6;
    const int q0   = (blockIdx.x * (BLOCK_THREADS / 64) + wid) * 2;  // 2 queries/wave
    const int q1   = q0 + 1;

    // Query points; nsq = -((x^2+y^2)+z^2) in exact np order.
    const float a0 = x[3 * q0], a1 = x[3 * q0 + 1], a2 = x[3 * q0 + 2];
    const float b0 = x[3 * q1], b1 = x[3 * q1 + 1], b2 = x[3 * q1 + 2];
    const float nsq0 = -__fadd_rn(__fadd_rn(__fmul_rn(a0, a0), __fmul_rn(a1, a1)), __fmul_rn(a2, a2));
    const float nsq1 = -__fadd_rn(__fadd_rn(__fmul_rn(b0, b0), __fmul_rn(b1, b1)), __fmul_rn(b2, b2));
    // Pre-doubled packed query coeffs (x2 exact; RN(2x*y)=2*RN(x*y), fma likewise:
    // pk chain == 2*dot of the reference fma chain, bitwise).
    const v2f c0A = {2.0f * a0, 2.0f * b0};
    const v2f c1A = {2.0f * a1, 2.0f * b1};
    const v2f c2A = {2.0f * a2, 2.0f * b2};

    // Lane-distributed sorted lists: lane r holds rank-r pair value (ascending) + idx.
    float    T0 = __uint_as_float(0x7F800000u), T1 = T0;  // +inf sentinels
    unsigned J0 = 0u, J1 = 0u;
    unsigned fK0 = 0xFF800000u, fK1 = 0xFF800000u;  // key(+inf): filter passes all
    float    fF0 = __uint_as_float(0x7F800000u), fF1 = fF0;

    for (int ph = 0; ph < NPHASE; ++ph) {
        __syncthreads();
        const int pbase = ph * PHASE_PTS;
#pragma unroll
        for (int kk = 0; kk < PHASE_PTS / BLOCK_THREADS; ++kk) {
            const int pl = tid + kk * BLOCK_THREADS;
            const int P  = pbase + pl;
            const float gx = x[3 * P], gy = x[3 * P + 1], gz = x[3 * P + 2];
            const float sq = __fadd_rn(__fadd_rn(__fmul_rn(gx, gx), __fmul_rn(gy, gy)),
                                       __fmul_rn(gz, gz));
            buf[pl] = make_float4(gx, gy, gz, sq);
        }
        __syncthreads();

#pragma unroll 4
        for (int tile = 0; tile < PHASE_PTS / 64; ++tile) {
            union F4 { float4 f4; v2f p[2]; float f[4]; } c;
            c.f4 = buf[tile * 64 + lane];
            v2f tA;
            // tA = 2*dot for both queries; broadcast point coord via op_sel
            asm("v_pk_mul_f32 %0, %1, %2 op_sel:[0,0] op_sel_hi:[0,1]"
                : "=v"(tA) : "v"(c.p[0]), "v"(c0A));
            asm("v_pk_fma_f32 %0, %1, %2, %3 op_sel:[1,0,0] op_sel_hi:[1,1,1]"
                : "=v"(tA) : "v"(c.p[0]), "v"(c1A), "v"(tA));
            asm("v_pk_fma_f32 %0, %1, %2, %3 op_sel:[0,0,0] op_sel_hi:[0,1,1]"
                : "=v"(tA) : "v"(c.p[1]), "v"(c2A), "v"(tA));
            // p = ((2dot + (-sq_i)) - sq_j): RN(x+(-y))==RN(x-y) -> bitwise == reference
            const float p0 = __fsub_rn(__fadd_rn(tA[0], nsq0), c.f[3]);
            const float p1 = __fsub_rn(__fadd_rn(tA[1], nsq1), c.f[3]);

            uint64_t m0 = __ballot(p0 < fF0);
            uint64_t m1 = __ballot(p1 < fF1);
            if (m0 | m1) {
                const int jbase = pbase + tile * 64;
                DRAIN(m0, p0, T0, J0, fK0, fF0)
                DRAIN(m1, p1, T1, J1, fK1, fF1)
            }
        }
    }

    // ranks 1..16 (rank 0 = overall farthest is dropped by the reference slicing)
    if (lane >= 1 && lane <= KOUT) {
        const int r = lane - 1;
        out_d[q0 * KOUT + r] = T0;
        out_i[q0 * KOUT + r] = (float)J0;
        out_d[q1 * KOUT + r] = T1;
        out_i[q1 * KOUT + r] = (float)J1;
    }
}

extern "C" void kernel_launch(void* const* d_in, const int* in_sizes, int n_in,
                              void* d_out, int out_size, void* d_ws, size_t ws_size,
                              hipStream_t stream) {
    const float* x = (const float*)d_in[0];
    float* out_d = (float*)d_out;              // 8*2048*16 dists
    float* out_i = out_d + (size_t)BN * KOUT;  // 8*2048*16 indices (as float)
    const int queries_per_block = 2 * (BLOCK_THREADS / 64);
    hipLaunchKernelGGL(knn_far_kernel, dim3(BN / queries_per_block), dim3(BLOCK_THREADS),
                       PHASE_PTS * sizeof(float4), stream, x, out_d, out_i);
}

// Round 6
// 161.036 us; speedup vs baseline: 1.2102x; 1.0636x over previous
//
#include <hip/hip_runtime.h>
#include <stdint.h>

#define BN            16384
#define PHASE_PTS     4096
#define NPHASE        4
#define BLOCK_THREADS 1024
#define KOUT          16

typedef float v2f __attribute__((ext_vector_type(2)));

// whole-wave shift-right by 1; lane 0 receives `oldv` (VALU DPP, no LDS pipe)
__device__ __forceinline__ unsigned wshr1(unsigned v, unsigned oldv) {
    return (unsigned)__builtin_amdgcn_update_dpp((int)oldv, (int)v, 0x138 /*WAVE_SHR:1*/,
                                                 0xF, 0xF, false);
}

// Minimal sorted insert of wave-uniform candidate (pc, jc) into the lane-
// distributed ascending list (T,J). No filter refresh in-loop: stale candidates
// fall into the sorted junk zone (lanes 17..63) harmlessly; the 64-lane array
// stays globally sorted. 9 VALU, carried chain ~4 ops, inserts pipeline.
#define DRAIN(m, p, T, J)                                                           \
    while (m) {                                                                     \
        const int b_ = (int)__builtin_ctzll(m);                                     \
        m &= m - 1;                                                                 \
        const float pc_ = __uint_as_float(                                          \
            (unsigned)__builtin_amdgcn_readlane(__float_as_int(p), b_));            \
        const unsigned jc_ = (unsigned)(jbase + b_);                                \
        const float Tup_ =                                                          \
            __uint_as_float(wshr1(__float_as_uint(T), 0xFF800000u /*-inf*/));       \
        const unsigned Jup_ = wshr1((J), 0u);                                       \
        const bool lt_ = (pc_ < Tup_);                                              \
        const float Tn_ = lt_ ? Tup_ : pc_;                                         \
        const unsigned Jn_ = lt_ ? Jup_ : jc_;                                      \
        const bool sel_ = (pc_ < (T));                                              \
        (T) = sel_ ? Tn_ : (T);                                                     \
        (J) = sel_ ? Jn_ : (J);                                                     \
    }

__global__ __launch_bounds__(BLOCK_THREADS) void knn_far_kernel(
    const float* __restrict__ x, float* __restrict__ out_d, float* __restrict__ out_i) {
    extern __shared__ float4 buf[];  // PHASE_PTS float4 = 64KB -> 2 blocks/CU, 32 waves/CU

    const int tid  = threadIdx.x;
    const int lane = tid & 63;
    const int wid  = tid >> 6;
    const int q0   = (blockIdx.x * (BLOCK_THREADS / 64) + wid) * 2;  // 2 queries/wave
    const int q1   = q0 + 1;

    // Query points; nsq = -((x^2+y^2)+z^2), exact np order then exact negation.
    const float a0 = x[3 * q0], a1 = x[3 * q0 + 1], a2 = x[3 * q0 + 2];
    const float b0 = x[3 * q1], b1 = x[3 * q1 + 1], b2 = x[3 * q1 + 2];
    const float nsq0 = -__fadd_rn(__fadd_rn(__fmul_rn(a0, a0), __fmul_rn(a1, a1)), __fmul_rn(a2, a2));
    const float nsq1 = -__fadd_rn(__fadd_rn(__fmul_rn(b0, b0), __fmul_rn(b1, b1)), __fmul_rn(b2, b2));
    const v2f nsq01 = {nsq0, nsq1};
    // Pre-doubled packed query coeffs (x2 exact; RN(2x*y)=2*RN(x*y), fma likewise:
    // pk chain == 2*dot of the reference fma chain, bitwise).
    const v2f c0A = {2.0f * a0, 2.0f * b0};
    const v2f c1A = {2.0f * a1, 2.0f * b1};
    const v2f c2A = {2.0f * a2, 2.0f * b2};

    // Lane-distributed sorted lists: lane r holds rank-r pair value (ascending) + idx.
    float    T0 = __uint_as_float(0x7F800000u), T1 = T0;  // +inf
    unsigned J0 = 0u, J1 = 0u;
    float    fF0 = T0, fF1 = T0;  // rank-16 filter (refreshed per dirty tile)

    for (int ph = 0; ph < NPHASE; ++ph) {
        __syncthreads();
        const int pbase = ph * PHASE_PTS;
#pragma unroll
        for (int kk = 0; kk < PHASE_PTS / BLOCK_THREADS; ++kk) {
            const int pl = tid + kk * BLOCK_THREADS;
            const int P  = pbase + pl;
            const float gx = x[3 * P], gy = x[3 * P + 1], gz = x[3 * P + 2];
            const float nsq = -__fadd_rn(__fadd_rn(__fmul_rn(gx, gx), __fmul_rn(gy, gy)),
                                         __fmul_rn(gz, gz));
            buf[pl] = make_float4(gx, gy, gz, nsq);  // store NEGATED sq
        }
        __syncthreads();

#pragma unroll 4
        for (int tile = 0; tile < PHASE_PTS / 64; ++tile) {
            union F4 { float4 f4; v2f p[2]; float f[4]; } c;
            c.f4 = buf[tile * 64 + lane];
            v2f d2;
            // d2 = 2*dot for both queries (broadcast point coord via op_sel)
            asm("v_pk_mul_f32 %0, %1, %2 op_sel:[0,0] op_sel_hi:[0,1]"
                : "=v"(d2) : "v"(c.p[0]), "v"(c0A));
            asm("v_pk_fma_f32 %0, %1, %2, %0 op_sel:[1,0,0] op_sel_hi:[1,1,1]"
                : "+v"(d2) : "v"(c.p[0]), "v"(c1A));
            asm("v_pk_fma_f32 %0, %1, %2, %0 op_sel:[0,0,0] op_sel_hi:[0,1,1]"
                : "+v"(d2) : "v"(c.p[1]), "v"(c2A));
            // d2 += (nsq_q0, nsq_q1)  [packed, per-query]
            asm("v_pk_add_f32 %0, %0, %1"
                : "+v"(d2) : "v"(nsq01));
            // d2 += (-sq_j) broadcast from hi half of c.p[1] (staged negated)
            asm("v_pk_add_f32 %0, %0, %1 op_sel:[0,1] op_sel_hi:[1,1]"
                : "+v"(d2) : "v"(c.p[1]));

            uint64_t m0 = __ballot(d2[0] < fF0);
            uint64_t m1 = __ballot(d2[1] < fF1);
            if (m0 | m1) {
                const int jbase = pbase + tile * 64;
                const float p0 = d2[0], p1 = d2[1];
                DRAIN(m0, p0, T0, J0)
                DRAIN(m1, p1, T1, J1)
                fF0 = __uint_as_float(
                    (unsigned)__builtin_amdgcn_readlane(__float_as_int(T0), 16));
                fF1 = __uint_as_float(
                    (unsigned)__builtin_amdgcn_readlane(__float_as_int(T1), 16));
            }
        }
    }

    // ranks 1..16 (rank 0 = overall farthest is dropped by the reference slicing)
    if (lane >= 1 && lane <= KOUT) {
        const int r = lane - 1;
        out_d[q0 * KOUT + r] = T0;
        out_i[q0 * KOUT + r] = (float)J0;
        out_d[q1 * KOUT + r] = T1;
        out_i[q1 * KOUT + r] = (float)J1;
    }
}

extern "C" void kernel_launch(void* const* d_in, const int* in_sizes, int n_in,
                              void* d_out, int out_size, void* d_ws, size_t ws_size,
                              hipStream_t stream) {
    const float* x = (const float*)d_in[0];
    float* out_d = (float*)d_out;              // 8*2048*16 dists
    float* out_i = out_d + (size_t)BN * KOUT;  // 8*2048*16 indices (as float)
    const int queries_per_block = 2 * (BLOCK_THREADS / 64);
    hipLaunchKernelGGL(knn_far_kernel, dim3(BN / queries_per_block), dim3(BLOCK_THREADS),
                       PHASE_PTS * sizeof(float4), stream, x, out_d, out_i);
}

// Round 7
// 142.105 us; speedup vs baseline: 1.3714x; 1.1332x over previous
//
#include <hip/hip_runtime.h>
#include <stdint.h>

#define BN            16384
#define PHASE_PTS     4096
#define NPHASE        4
#define BLOCK_THREADS 1024
#define NWAVES        (BLOCK_THREADS / 64)
#define KOUT          16

typedef float v2f __attribute__((ext_vector_type(2)));

// sortable key of float bits (ascending uint == ascending float)
__device__ __forceinline__ unsigned key_u(unsigned u) {
    return u ^ ((unsigned)((int)u >> 31) | 0x80000000u);
}
// whole-wave shift-right by 1; lane 0 receives `oldv` (VALU DPP, no LDS pipe)
__device__ __forceinline__ unsigned wshr1(unsigned v, unsigned oldv) {
    return (unsigned)__builtin_amdgcn_update_dpp((int)oldv, (int)v, 0x138 /*WAVE_SHR:1*/,
                                                 0xF, 0xF, false);
}
#define RL16(T) __uint_as_float((unsigned)__builtin_amdgcn_readlane(__float_as_int(T), 16))

// Minimal sorted insert (R6): stale candidates fall into the sorted junk zone.
#define DRAIN(m, p, T, J)                                                           \
    while (m) {                                                                     \
        const int b_ = (int)__builtin_ctzll(m);                                     \
        m &= m - 1;                                                                 \
        const float pc_ = __uint_as_float(                                          \
            (unsigned)__builtin_amdgcn_readlane(__float_as_int(p), b_));            \
        const unsigned jc_ = (unsigned)(jbase + b_);                                \
        const float Tup_ =                                                          \
            __uint_as_float(wshr1(__float_as_uint(T), 0xFF800000u /*-inf*/));       \
        const unsigned Jup_ = wshr1((J), 0u);                                       \
        const bool lt_ = (pc_ < Tup_);                                              \
        const float Tn_ = lt_ ? Tup_ : pc_;                                         \
        const unsigned Jn_ = lt_ ? Jup_ : jc_;                                      \
        const bool sel_ = (pc_ < (T));                                              \
        (T) = sel_ ? Tn_ : (T);                                                     \
        (J) = sel_ ? Jn_ : (J);                                                     \
    }

// Packed fast-path eval: d2 = ((2*dot + nsq_q) + nsq_j), bitwise == reference chain.
#define EVAL_TILE(tile)                                                             \
    union F4 { float4 f4; v2f p[2]; float f[4]; } c;                                \
    c.f4 = buf[(tile) * 64 + lane];                                                 \
    v2f d2;                                                                         \
    asm("v_pk_mul_f32 %0, %1, %2 op_sel:[0,0] op_sel_hi:[0,1]"                      \
        : "=v"(d2) : "v"(c.p[0]), "v"(c0A));                                        \
    asm("v_pk_fma_f32 %0, %1, %2, %0 op_sel:[1,0,0] op_sel_hi:[1,1,1]"              \
        : "+v"(d2) : "v"(c.p[0]), "v"(c1A));                                        \
    asm("v_pk_fma_f32 %0, %1, %2, %0 op_sel:[0,0,0] op_sel_hi:[0,1,1]"              \
        : "+v"(d2) : "v"(c.p[1]), "v"(c2A));                                        \
    asm("v_pk_add_f32 %0, %0, %1" : "+v"(d2) : "v"(nsq01));                         \
    asm("v_pk_add_f32 %0, %0, %1 op_sel:[0,1] op_sel_hi:[1,1]"                      \
        : "+v"(d2) : "v"(c.p[1]));

#define TILE_BODY(tile)                                                             \
    do {                                                                            \
        EVAL_TILE(tile)                                                             \
        uint64_t m0 = __ballot(d2[0] < fF0);                                        \
        uint64_t m1 = __ballot(d2[1] < fF1);                                        \
        if (m0 | m1) {                                                              \
            const int jbase = pbase + (tile) * 64;                                  \
            const float p0 = d2[0], p1 = d2[1];                                     \
            DRAIN(m0, p0, T0, J0)                                                   \
            DRAIN(m1, p1, T1, J1)                                                   \
            fF0 = RL16(T0);                                                         \
            fF1 = RL16(T1);                                                         \
        }                                                                           \
    } while (0)

#define STAGE_PHASE(ph)                                                             \
    do {                                                                            \
        const int pb_ = (ph) * PHASE_PTS;                                           \
        _Pragma("unroll")                                                           \
        for (int kk = 0; kk < PHASE_PTS / BLOCK_THREADS; ++kk) {                    \
            const int pl = tid + kk * BLOCK_THREADS;                                \
            const int P  = pb_ + pl;                                                \
            const float gx = x[3 * P], gy = x[3 * P + 1], gz = x[3 * P + 2];        \
            const float nsq = -__fadd_rn(                                           \
                __fadd_rn(__fmul_rn(gx, gx), __fmul_rn(gy, gy)), __fmul_rn(gz, gz));\
            buf[pl] = make_float4(gx, gy, gz, nsq);                                 \
        }                                                                           \
    } while (0)

// Wave-parallel exact sort of 64 (p, j=lane) pairs via rank computation.
// Ordering scalar: d = key(p)*64 + lane as a positive double (exact <= 2^38),
// so one f64 compare realizes (p asc, j asc). Wave-synchronous LDS: ds ops of
// one wave execute in program order -> no barriers needed.
__device__ __forceinline__ void presort64(float p, int lane, double* sw,
                                          float& T, unsigned& J) {
    const double dm = (double)key_u(__float_as_uint(p)) * 64.0 + (double)lane;
    sw[lane] = dm;
    unsigned rank = 0;
    const char* sb = (const char*)sw;
    unsigned off = (unsigned)lane * 8u;
#pragma unroll 7
    for (int s = 1; s < 64; ++s) {
        off = (off + 8u) & 511u;  // rotate: conflict-free
        const double dn = *(const double*)(sb + off);
        rank += (dn < dm) ? 1u : 0u;
    }
    // scatter (j<<32 | p_bits) to slot rank (ranks are a permutation), read back lane
    sw[rank] = __longlong_as_double(
        (long long)(((unsigned long long)(unsigned)lane << 32) | __float_as_uint(p)));
    const unsigned long long v = (unsigned long long)__double_as_longlong(sw[lane]);
    T = __uint_as_float((unsigned)(v & 0xFFFFFFFFull));
    J = (unsigned)(v >> 32);
}

__global__ __launch_bounds__(BLOCK_THREADS) void knn_far_kernel(
    const float* __restrict__ x, float* __restrict__ out_d, float* __restrict__ out_i) {
    extern __shared__ char smem[];  // 64KB tile buf + 8KB per-wave sort scratch
    float4* buf = (float4*)smem;
    double* sw  = (double*)(smem + PHASE_PTS * sizeof(float4)) + (threadIdx.x >> 6) * 64;

    const int tid  = threadIdx.x;
    const int lane = tid & 63;
    const int wid  = tid >> 6;
    const int q0   = (blockIdx.x * NWAVES + wid) * 2;  // 2 queries/wave
    const int q1   = q0 + 1;

    // Query points; nsq = -((x^2+y^2)+z^2), exact np order then exact negation.
    const float a0 = x[3 * q0], a1 = x[3 * q0 + 1], a2 = x[3 * q0 + 2];
    const float b0 = x[3 * q1], b1 = x[3 * q1 + 1], b2 = x[3 * q1 + 2];
    const float nsq0 = -__fadd_rn(__fadd_rn(__fmul_rn(a0, a0), __fmul_rn(a1, a1)), __fmul_rn(a2, a2));
    const float nsq1 = -__fadd_rn(__fadd_rn(__fmul_rn(b0, b0), __fmul_rn(b1, b1)), __fmul_rn(b2, b2));
    const v2f nsq01 = {nsq0, nsq1};
    // Pre-doubled packed query coeffs (x2 exact; pk chain == 2*dot of ref, bitwise).
    const v2f c0A = {2.0f * a0, 2.0f * b0};
    const v2f c1A = {2.0f * a1, 2.0f * b1};
    const v2f c2A = {2.0f * a2, 2.0f * b2};

    float    T0, T1;
    unsigned J0, J1;
    float    fF0, fF1;

    // ---- phase 0: stage, init lists from tile 0 via presort (no insert flood) ----
    {
        STAGE_PHASE(0);
        __syncthreads();
        const int pbase = 0;
        {
            EVAL_TILE(0)
            presort64(d2[0], lane, sw, T0, J0);
            presort64(d2[1], lane, sw, T1, J1);
            fF0 = RL16(T0);
            fF1 = RL16(T1);
        }
#pragma unroll 4
        for (int tile = 1; tile < PHASE_PTS / 64; ++tile) TILE_BODY(tile);
    }

    // ---- phases 1..3 ----
    for (int ph = 1; ph < NPHASE; ++ph) {
        __syncthreads();
        STAGE_PHASE(ph);
        __syncthreads();
        const int pbase = ph * PHASE_PTS;
#pragma unroll 4
        for (int tile = 0; tile < PHASE_PTS / 64; ++tile) TILE_BODY(tile);
    }

    // ranks 1..16 (rank 0 = overall farthest is dropped by the reference slicing)
    if (lane >= 1 && lane <= KOUT) {
        const int r = lane - 1;
        out_d[q0 * KOUT + r] = T0;
        out_i[q0 * KOUT + r] = (float)J0;
        out_d[q1 * KOUT + r] = T1;
        out_i[q1 * KOUT + r] = (float)J1;
    }
}

extern "C" void kernel_launch(void* const* d_in, const int* in_sizes, int n_in,
                              void* d_out, int out_size, void* d_ws, size_t ws_size,
                              hipStream_t stream) {
    const float* x = (const float*)d_in[0];
    float* out_d = (float*)d_out;              // 8*2048*16 dists
    float* out_i = out_d + (size_t)BN * KOUT;  // 8*2048*16 indices (as float)
    const int queries_per_block = 2 * NWAVES;
    const size_t shmem = PHASE_PTS * sizeof(float4) + NWAVES * 64 * sizeof(double);
    hipLaunchKernelGGL(knn_far_kernel, dim3(BN / queries_per_block), dim3(BLOCK_THREADS),
                       shmem, stream, x, out_d, out_i);
}